// Round 5
// baseline (337.036 us; speedup 1.0000x reference)
//
#include <hip/hip_runtime.h>
#include <hip/hip_bf16.h>

#define D_     256
#define TWO_DI 1024
#define DI_    512
#define NSTATE 16
#define RR     16
#define NDBL   48      // R + 2N
#define BSEQ   8
#define NC     256
#define NCHUNK 16
#define CLEN   16
#define CTX    2048    // 8*256
#define TGT    512     // 8*64

typedef __attribute__((ext_vector_type(8))) short short8v;
typedef __attribute__((ext_vector_type(8))) unsigned short ushort8v;
typedef __attribute__((ext_vector_type(4))) float floatx4;

__device__ __forceinline__ float siluf(float x) { return x / (1.f + __expf(-x)); }
__device__ __forceinline__ float softplusf(float x) {
  return fmaxf(x, 0.f) + log1pf(__expf(-fabsf(x)));
}
__device__ __forceinline__ unsigned short f2bf(float x) {
  unsigned u = __float_as_uint(x);
  u += 0x7fffu + ((u >> 16) & 1u);          // round-to-nearest-even
  return (unsigned short)(u >> 16);
}
__device__ __forceinline__ float bf2f(unsigned short b) {
  return __uint_as_float((unsigned)b << 16);
}

// ---- one-shot prep: W_in'(=g-scaled)/W_o/W_x transpose->bf16, WdtT, Aneg,
//      colsum(W_in') and b@W_in per column (atomicAdd into zeroed cs0/bW) ----
__global__ __launch_bounds__(256) void prep_all(
    const float* __restrict__ W_in, const float* __restrict__ W_o,
    const float* __restrict__ W_x, const float* __restrict__ Alog,
    const float* __restrict__ W_dt,
    const float* __restrict__ ln_g, const float* __restrict__ ln_b,
    unsigned short* __restrict__ Wint, unsigned short* __restrict__ Wot,
    unsigned short* __restrict__ Wxt, float* __restrict__ Aneg,
    float* __restrict__ WdtT, float* __restrict__ cs0, float* __restrict__ bW)
{
  __shared__ float tile[32][33];
  int b = blockIdx.x;
  int tx = threadIdx.x & 31, ty = threadIdx.x >> 5;
  if (b < 1024) {          // W_in: 4 x [256][1024] -> g-scaled bf16 [1024][256] + colsums
    int z = b >> 8, t = b & 255; int cx = t & 31, ry = t >> 5;
    const int R = 256, C = 1024;
    const float* src = W_in + (size_t)z * R * C;
    unsigned short* dst = Wint + (size_t)z * R * C;
    int c0 = cx * 32, r0 = ry * 32;
#pragma unroll
    for (int i = 0; i < 4; ++i)
      tile[ty + i * 8][tx] = src[(size_t)(r0 + ty + i * 8) * C + c0 + tx];
    __syncthreads();
    float gv  = ln_g[z * D_ + r0 + tx];
    float bev = ln_b[z * D_ + r0 + tx];
#pragma unroll
    for (int i = 0; i < 4; ++i) {
      int c = c0 + ty + i * 8;
      float wv = tile[tx][ty + i * 8];
      unsigned short h = f2bf(wv * gv);
      dst[(size_t)c * R + r0 + tx] = h;
      float cs = bf2f(h);          // colsum of the bf16-rounded g-scaled weight
      float bs = bev * wv;
#pragma unroll
      for (int off = 1; off <= 16; off <<= 1) {
        cs += __shfl_xor(cs, off);
        bs += __shfl_xor(bs, off);
      }
      if (tx == 0) {
        atomicAdd(&cs0[z * TWO_DI + c], cs);
        atomicAdd(&bW[z * TWO_DI + c], bs);
      }
    }
    return;
  }
  const float* src; unsigned short* dst; int R, C, cx, ry;
  if (b < 1536) {          // W_o: 4 x [512][256] -> [256][512]
    int bb = b - 1024; int z = bb >> 7, t = bb & 127; cx = t & 7; ry = t >> 3; R = 512; C = 256;
    src = W_o + (size_t)z * R * C; dst = Wot + (size_t)z * R * C;
  } else if (b < 1664) {   // W_x: 4 x [512][48] -> [48][512]
    int bb = b - 1536; int z = bb >> 5, t = bb & 31; cx = t & 1; ry = t >> 1; R = 512; C = 48;
    src = W_x + (size_t)z * R * C; dst = Wxt + (size_t)z * R * C;
  } else if (b < 1792) {   // Aneg
    int i = (b - 1664) * 256 + threadIdx.x;
    if (i < 4 * DI_ * NSTATE) Aneg[i] = -__expf(Alog[i]);
    return;
  } else {                 // WdtT: 4 x [16][512] -> [512][16]
    int i = (b - 1792) * 256 + threadIdx.x;   // 32768 total
    int z = i >> 13, rem = i & 8191, c = rem >> 4, r = rem & 15;
    WdtT[i] = W_dt[(size_t)z * RR * DI_ + r * DI_ + c];
    return;
  }
  int c0 = cx * 32, r0 = ry * 32;
#pragma unroll
  for (int i = 0; i < 4; ++i) {
    int r = r0 + ty + i * 8;
    tile[ty + i * 8][tx] = (r < R && c0 + tx < C) ? src[(size_t)r * C + c0 + tx] : 0.f;
  }
  __syncthreads();
#pragma unroll
  for (int i = 0; i < 4; ++i) {
    int c = c0 + ty + i * 8;
    if (c < C && r0 + tx < R)
      dst[(size_t)c * R + r0 + tx] = f2bf(tile[tx][ty + i * 8]);
  }
}

// ======== in-proj GEMM on RAW x (bf16), LN applied in epilogue via linearity:
//   out[col] = rstd*(acc - mu*cs0[col]) + bW[col]
// EPI=0 -> C (xz).  EPI=1 (tgt): col<512 -> silu(cconv+v*w3)->xcv_bf; else zbuf. ========
template<int EPI>
__device__ __forceinline__ void gemm_in_ln_body(
    unsigned short (*As)[72], unsigned short (*Bs)[72],
    float* mus, float* rstds, int bx, int by,
    const float* __restrict__ X, const unsigned short* __restrict__ Bt,
    const float* __restrict__ cs0, const float* __restrict__ bW,
    float* __restrict__ C,
    const float* __restrict__ cconv, const float* __restrict__ Wc4,
    unsigned short* __restrict__ xcv_bf, float* __restrict__ zbuf)
{
  const int K = D_, N = TWO_DI;
  int tid = threadIdx.x;
  int n0 = bx * 64, m0 = by * 64;
  int w = tid >> 6, lane = tid & 63;
  int lr = lane & 15, kq = lane >> 4;
  int wr = w >> 1, wc = w & 1;
  int srow = tid >> 2, q = tid & 3, schunk = q * 16;
  const float* Apf = &X[(size_t)(m0 + srow) * K];
  // load this thread's 4x16 column slices of its row once; stats from regs
  float4 xr[4][4];
#pragma unroll
  for (int j = 0; j < 4; ++j)
#pragma unroll
    for (int i = 0; i < 4; ++i)
      xr[j][i] = *reinterpret_cast<const float4*>(&Apf[j * 64 + schunk + i * 4]);
  float s = 0.f, sq = 0.f;
#pragma unroll
  for (int j = 0; j < 4; ++j)
#pragma unroll
    for (int i = 0; i < 4; ++i) {
      float4 v = xr[j][i];
      s  += v.x + v.y + v.z + v.w;
      sq += v.x * v.x + v.y * v.y + v.z * v.z + v.w * v.w;
    }
  s += __shfl_xor(s, 1);  s += __shfl_xor(s, 2);
  sq += __shfl_xor(sq, 1); sq += __shfl_xor(sq, 2);
  float mu   = s * (1.f / K);
  float rstd = rsqrtf(sq * (1.f / K) - mu * mu + 1e-5f);
  if (q == 0) { mus[srow] = mu; rstds[srow] = rstd; }
  const unsigned short* Bp = &Bt[(size_t)(n0 + srow) * K + schunk];
  ushort8v b0 = *reinterpret_cast<const ushort8v*>(Bp);
  ushort8v b1 = *reinterpret_cast<const ushort8v*>(Bp + 8);
  floatx4 acc[2][2] = {};
#pragma unroll
  for (int j = 0; j < 4; ++j) {
    __syncthreads();
    {
      ushort8v o0, o1;
#pragma unroll
      for (int i = 0; i < 4; ++i) {
        float4 v = xr[j][i];
        unsigned short e0 = f2bf(v.x), e1 = f2bf(v.y), e2 = f2bf(v.z), e3 = f2bf(v.w);
        if (i < 2) { o0[i*4] = (short)e0; o0[i*4+1] = (short)e1; o0[i*4+2] = (short)e2; o0[i*4+3] = (short)e3; }
        else { int jj = (i - 2) * 4; o1[jj] = (short)e0; o1[jj+1] = (short)e1; o1[jj+2] = (short)e2; o1[jj+3] = (short)e3; }
      }
      *reinterpret_cast<ushort8v*>(&As[srow][schunk])     = o0;
      *reinterpret_cast<ushort8v*>(&As[srow][schunk + 8]) = o1;
    }
    *reinterpret_cast<ushort8v*>(&Bs[srow][schunk])     = b0;
    *reinterpret_cast<ushort8v*>(&Bs[srow][schunk + 8]) = b1;
    __syncthreads();
    if (j < 3) {
      b0 = *reinterpret_cast<const ushort8v*>(Bp + j * 64 + 64);
      b1 = *reinterpret_cast<const ushort8v*>(Bp + j * 64 + 72);
    }
#pragma unroll
    for (int ks = 0; ks < 2; ++ks) {
      short8v af2[2], bf2v[2];
#pragma unroll
      for (int f = 0; f < 2; ++f)
        af2[f] = *reinterpret_cast<const short8v*>(&As[wr * 32 + f * 16 + lr][ks * 32 + kq * 8]);
#pragma unroll
      for (int g2 = 0; g2 < 2; ++g2)
        bf2v[g2] = *reinterpret_cast<const short8v*>(&Bs[wc * 32 + g2 * 16 + lr][ks * 32 + kq * 8]);
#pragma unroll
      for (int f = 0; f < 2; ++f)
#pragma unroll
        for (int g2 = 0; g2 < 2; ++g2)
          acc[f][g2] = __builtin_amdgcn_mfma_f32_16x16x32_bf16(af2[f], bf2v[g2], acc[f][g2], 0, 0, 0);
    }
  }
#pragma unroll
  for (int f = 0; f < 2; ++f)
#pragma unroll
    for (int g2 = 0; g2 < 2; ++g2) {
      int col = n0 + wc * 32 + g2 * 16 + lr;
      float c0v = cs0[col], bwv = bW[col];
#pragma unroll
      for (int r = 0; r < 4; ++r) {
        int rowl = wr * 32 + f * 16 + kq * 4 + r;
        int row  = m0 + rowl;
        float v = rstds[rowl] * (acc[f][g2][r] - mus[rowl] * c0v) + bwv;
        if (EPI == 0) {
          C[(size_t)row * N + col] = v;
        } else {
          int bb = row >> 6;
          if (col < DI_) {
            float sv = siluf(cconv[bb * DI_ + col] + v * Wc4[col * 4 + 3]);
            xcv_bf[(size_t)row * DI_ + col] = f2bf(sv);
          } else {
            zbuf[(size_t)row * DI_ + (col - DI_)] = v;
          }
        }
      }
    }
}

template<int EPI>
__global__ __launch_bounds__(256) void gemm_in_ln(
    const float* __restrict__ X, const unsigned short* __restrict__ Bt,
    const float* __restrict__ cs0, const float* __restrict__ bW,
    float* __restrict__ C,
    const float* __restrict__ cconv, const float* __restrict__ Wc4,
    unsigned short* __restrict__ xcv_bf, float* __restrict__ zbuf)
{
  __shared__ unsigned short As[64][72];
  __shared__ unsigned short Bs[64][72];
  __shared__ float mus[64], rstds[64];
  gemm_in_ln_body<EPI>(As, Bs, mus, rstds, blockIdx.x, blockIdx.y,
                       X, Bt, cs0, bW, C, cconv, Wc4, xcv_bf, zbuf);
}

// fused: A in-proj (512 blocks) + B in-proj EPI=1 (128 blocks)
__global__ __launch_bounds__(256) void fused_gemm_in_ln(
    const float* __restrict__ Xa, const unsigned short* __restrict__ Bta,
    const float* __restrict__ cs0a, const float* __restrict__ bWa,
    float* __restrict__ Ca,
    const float* __restrict__ Xb, const unsigned short* __restrict__ Btb,
    const float* __restrict__ cs0b, const float* __restrict__ bWb,
    const float* __restrict__ cconv, const float* __restrict__ Wc4,
    unsigned short* __restrict__ xcv_bf, float* __restrict__ zbuf)
{
  __shared__ unsigned short As[64][72];
  __shared__ unsigned short Bs[64][72];
  __shared__ float mus[64], rstds[64];
  int f = blockIdx.x;
  if (f < 512)
    gemm_in_ln_body<0>(As, Bs, mus, rstds, f & 15, f >> 4, Xa, Bta, cs0a, bWa,
                       Ca, nullptr, nullptr, nullptr, nullptr);
  else {
    f -= 512;
    gemm_in_ln_body<1>(As, Bs, mus, rstds, f & 15, f >> 4, Xb, Btb, cs0b, bWb,
                       nullptr, cconv, Wc4, xcv_bf, zbuf);
  }
}

// ------- out-proj MFMA GEMM, 64x64 tile, bf16 A, +resid -------
__global__ __launch_bounds__(256) void gemm_out(
    const unsigned short* __restrict__ A, const unsigned short* __restrict__ Bt,
    const float* __restrict__ resid, float* __restrict__ C, int N, int K)
{
  __shared__ unsigned short As[64][72];
  __shared__ unsigned short Bs[64][72];
  int tid = threadIdx.x;
  int n0 = blockIdx.x * 64, m0 = blockIdx.y * 64;
  int w = tid >> 6, lane = tid & 63;
  int lr = lane & 15, kq = lane >> 4;
  int wr = w >> 1, wc = w & 1;
  int srow = tid >> 2, schunk = (tid & 3) * 16;
  const unsigned short* Ap = &A[(size_t)(m0 + srow) * K + schunk];
  const unsigned short* Bp = &Bt[(size_t)(n0 + srow) * K + schunk];
  ushort8v a0 = *reinterpret_cast<const ushort8v*>(Ap);
  ushort8v a1 = *reinterpret_cast<const ushort8v*>(Ap + 8);
  ushort8v b0 = *reinterpret_cast<const ushort8v*>(Bp);
  ushort8v b1 = *reinterpret_cast<const ushort8v*>(Bp + 8);
  floatx4 acc[2][2] = {};
  for (int k0 = 0; k0 < K; k0 += 64) {
    __syncthreads();
    *reinterpret_cast<ushort8v*>(&As[srow][schunk])     = a0;
    *reinterpret_cast<ushort8v*>(&As[srow][schunk + 8]) = a1;
    *reinterpret_cast<ushort8v*>(&Bs[srow][schunk])     = b0;
    *reinterpret_cast<ushort8v*>(&Bs[srow][schunk + 8]) = b1;
    __syncthreads();
    if (k0 + 64 < K) {
      a0 = *reinterpret_cast<const ushort8v*>(Ap + k0 + 64);
      a1 = *reinterpret_cast<const ushort8v*>(Ap + k0 + 72);
      b0 = *reinterpret_cast<const ushort8v*>(Bp + k0 + 64);
      b1 = *reinterpret_cast<const ushort8v*>(Bp + k0 + 72);
    }
#pragma unroll
    for (int ks = 0; ks < 2; ++ks) {
      short8v af[2], bf2v[2];
#pragma unroll
      for (int f = 0; f < 2; ++f)
        af[f] = *reinterpret_cast<const short8v*>(&As[wr * 32 + f * 16 + lr][ks * 32 + kq * 8]);
#pragma unroll
      for (int g2 = 0; g2 < 2; ++g2)
        bf2v[g2] = *reinterpret_cast<const short8v*>(&Bs[wc * 32 + g2 * 16 + lr][ks * 32 + kq * 8]);
#pragma unroll
      for (int f = 0; f < 2; ++f)
#pragma unroll
        for (int g2 = 0; g2 < 2; ++g2)
          acc[f][g2] = __builtin_amdgcn_mfma_f32_16x16x32_bf16(af[f], bf2v[g2], acc[f][g2], 0, 0, 0);
    }
  }
#pragma unroll
  for (int f = 0; f < 2; ++f)
#pragma unroll
    for (int g2 = 0; g2 < 2; ++g2) {
      int col = n0 + wc * 32 + g2 * 16 + lr;
#pragma unroll
      for (int r = 0; r < 4; ++r) {
        int row = m0 + wr * 32 + f * 16 + kq * 4 + r;
        float v = acc[f][g2][r] + resid[(size_t)row * N + col];
        C[(size_t)row * N + col] = v;
      }
    }
}

// ------- small-tile MFMA GEMM: 32x32 tile (tgt out-proj) -------
__device__ __forceinline__ void gemm_s_body(int bx, int by,
    const unsigned short* __restrict__ A, const unsigned short* __restrict__ Bt,
    const float* __restrict__ resid, float* __restrict__ C, int N, int K)
{
  __shared__ unsigned short As[32][72];
  __shared__ unsigned short Bs[32][72];
  int tid = threadIdx.x;
  int n0 = bx * 32, m0 = by * 32;
  int w = tid >> 6, lane = tid & 63;
  int lr = lane & 15, kq = lane >> 4;
  int wr = w >> 1, wc = w & 1;
  int srow = tid >> 3, schunk = (tid & 7) * 8;
  const unsigned short* Ap = &A[(size_t)(m0 + srow) * K + schunk];
  const unsigned short* Bp = &Bt[(size_t)(n0 + srow) * K + schunk];
  ushort8v a0 = *reinterpret_cast<const ushort8v*>(Ap);
  ushort8v b0 = *reinterpret_cast<const ushort8v*>(Bp);
  floatx4 acc = {};
  for (int k0 = 0; k0 < K; k0 += 64) {
    __syncthreads();
    *reinterpret_cast<ushort8v*>(&As[srow][schunk]) = a0;
    *reinterpret_cast<ushort8v*>(&Bs[srow][schunk]) = b0;
    __syncthreads();
    if (k0 + 64 < K) {
      a0 = *reinterpret_cast<const ushort8v*>(Ap + k0 + 64);
      b0 = *reinterpret_cast<const ushort8v*>(Bp + k0 + 64);
    }
#pragma unroll
    for (int ks = 0; ks < 2; ++ks) {
      short8v af = *reinterpret_cast<const short8v*>(&As[wr * 16 + lr][ks * 32 + kq * 8]);
      short8v bf = *reinterpret_cast<const short8v*>(&Bs[wc * 16 + lr][ks * 32 + kq * 8]);
      acc = __builtin_amdgcn_mfma_f32_16x16x32_bf16(af, bf, acc, 0, 0, 0);
    }
  }
  int col = n0 + wc * 16 + lr;
#pragma unroll
  for (int r = 0; r < 4; ++r) {
    int row = m0 + wr * 16 + kq * 4 + r;
    float v = acc[r] + resid[(size_t)row * N + col];
    C[(size_t)row * N + col] = v;
  }
}

__global__ __launch_bounds__(256) void gemm_s(
    const unsigned short* __restrict__ A, const unsigned short* __restrict__ Bt,
    const float* __restrict__ resid, float* __restrict__ C, int N, int K)
{
  gemm_s_body(blockIdx.x, blockIdx.y, A, Bt, resid, C, N, K);
}

// ===== ctx conv + dbl + dt + S,P all in one: dt/x stay in registers for the
// chunk-local scan (thread = channel, h/p recurrences = 16 parallel n-chains) =====
__device__ __forceinline__ void conv_sp_body(int blk,
    const float* __restrict__ xz, const float* __restrict__ Wc,
    const float* __restrict__ bc, const unsigned short* __restrict__ Wxt,
    const float* __restrict__ WdtT, const float* __restrict__ bdt,
    const float* __restrict__ Aneg,
    unsigned short* __restrict__ xcvb, float* __restrict__ dtb,
    float* __restrict__ dblg, float* __restrict__ cconv,
    float* __restrict__ Sb, float* __restrict__ Pb)
{
  __shared__ unsigned short xcs[16][528];
  __shared__ float dbl_s[16][48];
  int seq = blk >> 4, ch = blk & 15;
  int tok0 = blk * 16;
  int tid = threadIdx.x;
  int base = ch * 16;
  float xv_t[2][16], dt_t[2][16];
  // ---- conv + silu, taps reg-cached ----
#pragma unroll
  for (int hh = 0; hh < 2; ++hh) {
    int c = tid + hh * 256;
    const float4 wv = *reinterpret_cast<const float4*>(&Wc[c * 4]);
    float bcv = bc[c];
    const float* xzs = &xz[(size_t)(seq * NC) * TWO_DI + c];
    float r[19];
#pragma unroll
    for (int i = 0; i < 19; ++i) {
      int tl = base - 3 + i;
      r[i] = (tl >= 0) ? xzs[(size_t)tl * TWO_DI] : 0.f;
    }
#pragma unroll
    for (int t = 0; t < 16; ++t) {
      float a = bcv + r[t] * wv.x + r[t + 1] * wv.y + r[t + 2] * wv.z + r[t + 3] * wv.w;
      unsigned short sv = f2bf(siluf(a));
      xcs[t][c] = sv;
      xcvb[(size_t)(tok0 + t) * DI_ + c] = sv;
      xv_t[hh][t] = bf2f(sv);
    }
    if (ch == 15)
      cconv[seq * DI_ + c] = bcv + r[16] * wv.x + r[17] * wv.y + r[18] * wv.z;
  }
  __syncthreads();
  // ---- dbl = xcv @ Wx^T via MFMA (3 waves) ----
  int w = tid >> 6, lane = tid & 63, lr = lane & 15, kq = lane >> 4;
  if (w < 3) {
    floatx4 acc = {};
#pragma unroll
    for (int kc = 0; kc < 16; ++kc) {
      short8v bb = *reinterpret_cast<const short8v*>(&Wxt[(size_t)(w * 16 + lr) * DI_ + kc * 32 + kq * 8]);
      short8v aa = *reinterpret_cast<const short8v*>(&xcs[lr][kc * 32 + kq * 8]);
      acc = __builtin_amdgcn_mfma_f32_16x16x32_bf16(aa, bb, acc, 0, 0, 0);
    }
#pragma unroll
    for (int r2 = 0; r2 < 4; ++r2) {
      int t = kq * 4 + r2, col = w * 16 + lr;
      dbl_s[t][col] = acc[r2];
      dblg[(size_t)(tok0 + t) * NDBL + col] = acc[r2];
    }
  }
  __syncthreads();
  // ---- dt = softplus(dbl[:, :16] @ Wdt + bdt), kept in registers ----
#pragma unroll
  for (int hh = 0; hh < 2; ++hh) {
    int c = tid + hh * 256;
    float wr_[16];
    const float4* wt4 = reinterpret_cast<const float4*>(&WdtT[c * 16]);
#pragma unroll
    for (int qq = 0; qq < 4; ++qq) {
      float4 v4 = wt4[qq];
      wr_[qq * 4] = v4.x; wr_[qq * 4 + 1] = v4.y; wr_[qq * 4 + 2] = v4.z; wr_[qq * 4 + 3] = v4.w;
    }
    float bv = bdt[c];
#pragma unroll
    for (int t = 0; t < 16; ++t) {
      float accd = bv;
#pragma unroll
      for (int r2 = 0; r2 < 16; ++r2) accd += dbl_s[t][r2] * wr_[r2];
      float dtv = softplusf(accd);
      dt_t[hh][t] = dtv;
      dtb[(size_t)(tok0 + t) * DI_ + c] = dtv;
    }
  }
  // ---- chunk-local S,P from h=0: per-channel register recurrence over t ----
#pragma unroll
  for (int hh = 0; hh < 2; ++hh) {
    int d = tid + hh * 256;
    float An[16];
    const float4* An4 = reinterpret_cast<const float4*>(&Aneg[d * NSTATE]);
#pragma unroll
    for (int qq = 0; qq < 4; ++qq) {
      float4 a = An4[qq];
      An[qq * 4] = a.x; An[qq * 4 + 1] = a.y; An[qq * 4 + 2] = a.z; An[qq * 4 + 3] = a.w;
    }
    float h_n[16], p_n[16];
#pragma unroll
    for (int n = 0; n < 16; ++n) { h_n[n] = 0.f; p_n[n] = 1.f; }
#pragma unroll
    for (int t = 0; t < 16; ++t) {
      float dtv  = dt_t[hh][t];
      float coef = dtv * xv_t[hh][t];
      float4 B0 = *reinterpret_cast<const float4*>(&dbl_s[t][RR]);
      float4 B1 = *reinterpret_cast<const float4*>(&dbl_s[t][RR + 4]);
      float4 B2 = *reinterpret_cast<const float4*>(&dbl_s[t][RR + 8]);
      float4 B3 = *reinterpret_cast<const float4*>(&dbl_s[t][RR + 12]);
      float Bv[16] = {B0.x, B0.y, B0.z, B0.w, B1.x, B1.y, B1.z, B1.w,
                      B2.x, B2.y, B2.z, B2.w, B3.x, B3.y, B3.z, B3.w};
#pragma unroll
      for (int n = 0; n < 16; ++n) {
        float dA = __expf(dtv * An[n]);
        h_n[n] = fmaf(dA, h_n[n], coef * Bv[n]);
        p_n[n] *= dA;
      }
    }
    size_t ob = ((size_t)blk * DI_ + d) * NSTATE;
#pragma unroll
    for (int qq = 0; qq < 4; ++qq) {
      *reinterpret_cast<float4*>(&Sb[ob + qq * 4]) =
          make_float4(h_n[qq*4], h_n[qq*4+1], h_n[qq*4+2], h_n[qq*4+3]);
      *reinterpret_cast<float4*>(&Pb[ob + qq * 4]) =
          make_float4(p_n[qq*4], p_n[qq*4+1], p_n[qq*4+2], p_n[qq*4+3]);
    }
  }
}

__global__ __launch_bounds__(256) void conv_sp_kern(
    const float* __restrict__ xz, const float* __restrict__ Wc,
    const float* __restrict__ bc, const unsigned short* __restrict__ Wxt,
    const float* __restrict__ WdtT, const float* __restrict__ bdt,
    const float* __restrict__ Aneg,
    unsigned short* __restrict__ xcvb, float* __restrict__ dtb,
    float* __restrict__ dblg, float* __restrict__ cconv,
    float* __restrict__ Sb, float* __restrict__ Pb)
{
  conv_sp_body(blockIdx.x, xz, Wc, bc, Wxt, WdtT, bdt, Aneg,
               xcvb, dtb, dblg, cconv, Sb, Pb);
}

// ---- scan finalize: prefix-combine entry state, re-scan chunk, C-reduce + gate ----
__device__ __forceinline__ void sf_body(int b,
    const float* __restrict__ dblg, const unsigned short* __restrict__ xcvb,
    const float* __restrict__ xz, const float* __restrict__ dtb,
    const float* __restrict__ Sb, const float* __restrict__ Pb,
    const float* __restrict__ Aneg, const float* __restrict__ Dp,
    unsigned short* __restrict__ yb, float* __restrict__ hstate)
{
  int dg = b & 31, sc = b >> 5;
  int seq = sc >> 4, chunk = sc & 15;
  int tid = threadIdx.x;
  int tt = tid >> 4, cc = tid & 15;
  int tok0 = sc * CLEN;
  __shared__ float dts[16][17], xs[16][17], zs[16][17], Bsh[16][17], Csh[16][17], ys[16][17];
  dts[tt][cc] = dtb[(size_t)(tok0 + tt) * DI_ + dg * 16 + cc];
  xs[tt][cc]  = bf2f(xcvb[(size_t)(tok0 + tt) * DI_ + dg * 16 + cc]);
  zs[tt][cc]  = xz[(size_t)(tok0 + tt) * TWO_DI + DI_ + dg * 16 + cc];
  Bsh[tt][cc] = dblg[(size_t)(tok0 + tt) * NDBL + RR + cc];
  Csh[tt][cc] = dblg[(size_t)(tok0 + tt) * NDBL + RR + NSTATE + cc];
  __syncthreads();
  int dl = tt, n = cc;
  int d = dg * 16 + dl;
  float A  = Aneg[d * NSTATE + n];
  float Dv = Dp[d];
  float Bn[16], Cn[16];
#pragma unroll
  for (int t = 0; t < CLEN; ++t) { Bn[t] = Bsh[t][n]; Cn[t] = Csh[t][n]; }
  float h = 0.f;
  for (int c2 = 0; c2 < chunk; ++c2) {
    size_t o = ((size_t)(seq * NCHUNK + c2) * DI_ + d) * NSTATE + n;
    h = fmaf(Pb[o], h, Sb[o]);
  }
#pragma unroll
  for (int t = 0; t < CLEN; ++t) {
    float dtv = dts[t][dl];
    float xv  = xs[t][dl];
    float dA  = __expf(dtv * A);
    h = fmaf(dA, h, dtv * xv * Bn[t]);
    float p = h * Cn[t];
    p += __shfl_xor(p, 1); p += __shfl_xor(p, 2);
    p += __shfl_xor(p, 4); p += __shfl_xor(p, 8);
    if (n == 0) ys[t][dl] = (p + xv * Dv) * siluf(zs[t][dl]);
  }
  __syncthreads();
  yb[(size_t)(tok0 + tt) * DI_ + dg * 16 + cc] = f2bf(ys[tt][cc]);
  if (chunk == NCHUNK - 1)
    hstate[(size_t)seq * DI_ * NSTATE + d * NSTATE + n] = h;
}

__global__ __launch_bounds__(256) void scan_fin(
    const float* __restrict__ dblg, const unsigned short* __restrict__ xcvb,
    const float* __restrict__ xz, const float* __restrict__ dtb,
    const float* __restrict__ Sb, const float* __restrict__ Pb,
    const float* __restrict__ Aneg, const float* __restrict__ Dp,
    unsigned short* __restrict__ yb, float* __restrict__ hstate)
{
  sf_body(blockIdx.x, dblg, xcvb, xz, dtb, Sb, Pb, Aneg, Dp, yb, hstate);
}

// fused: B out-proj gemm_s (128 blocks first) + A scan_fin (4096 blocks)
__global__ __launch_bounds__(256) void fused_fin_gout(
    const unsigned short* __restrict__ Ag, const unsigned short* __restrict__ Btg,
    const float* __restrict__ residg, float* __restrict__ Cg,
    const float* __restrict__ dblg, const unsigned short* __restrict__ xcvb,
    const float* __restrict__ xz, const float* __restrict__ dtb,
    const float* __restrict__ Sb, const float* __restrict__ Pb,
    const float* __restrict__ Aneg, const float* __restrict__ Dp,
    unsigned short* __restrict__ yb, float* __restrict__ hstate)
{
  if (blockIdx.x < 128) {
    int f = blockIdx.x;
    gemm_s_body(f & 7, f >> 3, Ag, Btg, residg, Cg, D_, DI_);
  } else {
    sf_body(blockIdx.x - 128, dblg, xcvb, xz, dtb, Sb, Pb, Aneg, Dp, yb, hstate);
  }
}

// ---- target SSM, 256 block-ids = (32 token-groups) x (8 ch-groups of 64). ----
__device__ __forceinline__ void ssm_body(int blk,
    const unsigned short* __restrict__ xcv_bf, const float* __restrict__ zbuf,
    const unsigned short* __restrict__ Wx, const float* __restrict__ WdtT_l,
    const float* __restrict__ bdt_l, const float* __restrict__ An_l,
    const float* __restrict__ Dp_l, const float* __restrict__ hs,
    unsigned short* __restrict__ ybf)
{
  __shared__ float dbl_s[16][48];
  int tg = blk >> 3, cg = blk & 7;
  int tok0 = tg * 16;
  int b = tg >> 2;
  int tid = threadIdx.x;
  int w = tid >> 6, lane = tid & 63, lr = lane & 15, kq = lane >> 4;
  if (w < 3) {
    floatx4 acc = {};
#pragma unroll
    for (int kc = 0; kc < 16; ++kc) {
      short8v bb = *reinterpret_cast<const short8v*>(&Wx[(size_t)(w * 16 + lr) * DI_ + kc * 32 + kq * 8]);
      short8v aa = *reinterpret_cast<const short8v*>(&xcv_bf[(size_t)(tok0 + lr) * DI_ + kc * 32 + kq * 8]);
      acc = __builtin_amdgcn_mfma_f32_16x16x32_bf16(aa, bb, acc, 0, 0, 0);
    }
#pragma unroll
    for (int r = 0; r < 4; ++r)
      dbl_s[kq * 4 + r][w * 16 + lr] = acc[r];
  }
  __syncthreads();
  int c = cg * 64 + (tid & 63);
  int t0 = (tid >> 6) * 4;
  float wdt_r[16], An[16], hr[16];
  const float4* wt4 = reinterpret_cast<const float4*>(&WdtT_l[c * 16]);
  const float4* An4 = reinterpret_cast<const float4*>(&An_l[c * NSTATE]);
  const float4* hr4 = reinterpret_cast<const float4*>(&hs[(size_t)b * DI_ * NSTATE + c * NSTATE]);
#pragma unroll
  for (int qq = 0; qq < 4; ++qq) {
    float4 wv = wt4[qq]; wdt_r[qq*4]=wv.x; wdt_r[qq*4+1]=wv.y; wdt_r[qq*4+2]=wv.z; wdt_r[qq*4+3]=wv.w;
    float4 a = An4[qq]; An[qq*4]=a.x; An[qq*4+1]=a.y; An[qq*4+2]=a.z; An[qq*4+3]=a.w;
    float4 hv = hr4[qq]; hr[qq*4]=hv.x; hr[qq*4+1]=hv.y; hr[qq*4+2]=hv.z; hr[qq*4+3]=hv.w;
  }
  float Dv = Dp_l[c], bv = bdt_l[c];
#pragma unroll
  for (int tt = 0; tt < 4; ++tt) {
    int t = t0 + tt;
    float accd = bv;
#pragma unroll
    for (int r = 0; r < 16; ++r) accd += dbl_s[t][r] * wdt_r[r];
    float dtv = softplusf(accd);
    float xv = bf2f(xcv_bf[(size_t)(tok0 + t) * DI_ + c]);
    float coef = dtv * xv;
    float y = 0.f;
#pragma unroll
    for (int n = 0; n < 16; ++n) {
      float hn = fmaf(__expf(dtv * An[n]), hr[n], coef * dbl_s[t][RR + n]);
      y = fmaf(hn, dbl_s[t][RR + NSTATE + n], y);
    }
    float yv = (y + xv * Dv) * siluf(zbuf[(size_t)(tok0 + t) * DI_ + c]);
    ybf[(size_t)(tok0 + t) * DI_ + c] = f2bf(yv);
  }
}

__global__ __launch_bounds__(256) void tgt_ssm2(
    const unsigned short* __restrict__ xcv_bf, const float* __restrict__ zbuf,
    const unsigned short* __restrict__ Wx, const float* __restrict__ WdtT_l,
    const float* __restrict__ bdt_l, const float* __restrict__ An_l,
    const float* __restrict__ Dp_l, const float* __restrict__ hs,
    unsigned short* __restrict__ ybf)
{
  ssm_body(blockIdx.x, xcv_bf, zbuf, Wx, WdtT_l, bdt_l, An_l, Dp_l, hs, ybf);
}

// fused: conv+sp for A layer (128 blocks) + tgt SSM for B layer (256 blocks)
__global__ __launch_bounds__(256) void fused_convsp_ssm(
    const float* __restrict__ xz, const float* __restrict__ Wc,
    const float* __restrict__ bc, const unsigned short* __restrict__ WxtA,
    const float* __restrict__ WdtTA, const float* __restrict__ bdtA,
    const float* __restrict__ AnegA,
    unsigned short* __restrict__ xcvb, float* __restrict__ dtb,
    float* __restrict__ dblg, float* __restrict__ cconv,
    float* __restrict__ Sb, float* __restrict__ Pb,
    const unsigned short* __restrict__ xcv_bfB, const float* __restrict__ zbufB,
    const unsigned short* __restrict__ WxB, const float* __restrict__ WdtTB,
    const float* __restrict__ bdtB, const float* __restrict__ AnB,
    const float* __restrict__ DpB, const float* __restrict__ hsB,
    unsigned short* __restrict__ ybfB)
{
  if (blockIdx.x < BSEQ * NCHUNK)
    conv_sp_body(blockIdx.x, xz, Wc, bc, WxtA, WdtTA, bdtA, AnegA,
                 xcvb, dtb, dblg, cconv, Sb, Pb);
  else
    ssm_body(blockIdx.x - BSEQ * NCHUNK, xcv_bfB, zbufB, WxB, WdtTB, bdtB,
             AnB, DpB, hsB, ybfB);
}

extern "C" void kernel_launch(void* const* d_in, const int* in_sizes, int n_in,
                              void* d_out, int out_size, void* d_ws, size_t ws_size,
                              hipStream_t stream)
{
  const float* xc   = (const float*)d_in[0];
  const float* xt   = (const float*)d_in[1];
  const float* ln_g = (const float*)d_in[2];
  const float* ln_b = (const float*)d_in[3];
  const float* W_in = (const float*)d_in[4];
  const float* W_cv = (const float*)d_in[5];
  const float* b_cv = (const float*)d_in[6];
  const float* W_x  = (const float*)d_in[7];
  const float* W_dt = (const float*)d_in[8];
  const float* b_dt = (const float*)d_in[9];
  const float* Alog = (const float*)d_in[10];
  const float* Dp   = (const float*)d_in[11];
  const float* W_o  = (const float*)d_in[12];
  float* out = (float*)d_out;

  float* ws = (float*)d_ws;
  size_t off = 0;
  auto alloc = [&](size_t n) { float* p = ws + off; off += n; return p; };
  float* xz     = alloc((size_t)CTX * TWO_DI);
  float* dtb    = alloc((size_t)CTX * DI_);
  float* dblg   = alloc((size_t)CTX * NDBL);
  float* xcur   = alloc((size_t)CTX * D_);
  float* Sb     = alloc((size_t)BSEQ * NCHUNK * DI_ * NSTATE);
  float* Pb     = alloc((size_t)BSEQ * NCHUNK * DI_ * NSTATE);
  float* cconvT = alloc((size_t)4 * BSEQ * DI_);
  float* hst    = alloc((size_t)4 * BSEQ * DI_ * NSTATE);
  float* Aneg   = alloc((size_t)4 * DI_ * NSTATE);
  float* WdtT   = alloc((size_t)4 * DI_ * RR);
  float* cs0b   = alloc((size_t)4 * TWO_DI);   // colsum(W') per layer
  float* bWb    = alloc((size_t)4 * TWO_DI);   // b@W per layer (contiguous w/ cs0b)
  float* zbufB  = alloc((size_t)TGT * DI_);
  float* xtb    = alloc((size_t)TGT * D_);
  unsigned short* xcvb    = (unsigned short*)alloc((size_t)CTX * DI_ / 2);
  unsigned short* yb_bf   = (unsigned short*)alloc((size_t)CTX * DI_ / 2);
  unsigned short* xcv_bfB = (unsigned short*)alloc((size_t)TGT * DI_ / 2);
  unsigned short* y_bfB   = (unsigned short*)alloc((size_t)TGT * DI_ / 2);
  unsigned short* Wint    = (unsigned short*)alloc((size_t)4 * TWO_DI * D_ / 2);
  unsigned short* Wot     = (unsigned short*)alloc((size_t)4 * D_ * DI_ / 2);
  unsigned short* Wxt     = (unsigned short*)alloc((size_t)4 * NDBL * DI_ / 2);
  if (off * sizeof(float) > ws_size) return;

  hipMemsetAsync(cs0b, 0, (size_t)8 * TWO_DI * sizeof(float), stream);
  prep_all<<<1920, 256, 0, stream>>>(W_in, W_o, W_x, Alog, W_dt, ln_g, ln_b,
                                     Wint, Wot, Wxt, Aneg, WdtT, cs0b, bWb);

  // -------- A0: in-proj(epilogue-LN) -> conv+sp -> fin -> out-proj --------
  gemm_in_ln<0><<<dim3(16, CTX / 64), 256, 0, stream>>>(
      xc, Wint, cs0b, bWb, xz, nullptr, nullptr, nullptr, nullptr);
  conv_sp_kern<<<BSEQ * NCHUNK, 256, 0, stream>>>(
      xz, W_cv, b_cv, Wxt, WdtT, b_dt, Aneg, xcvb, dtb, dblg, cconvT, Sb, Pb);
  scan_fin<<<BSEQ * NCHUNK * 32, 256, 0, stream>>>(
      dblg, xcvb, xz, dtb, Sb, Pb, Aneg, Dp, yb_bf, hst);
  gemm_out<<<dim3(D_ / 64, CTX / 64), 256, 0, stream>>>(
      yb_bf, Wot, xc, xcur, D_, DI_);

  // -------- groups: A(l+1) co-scheduled with B(l) --------
  for (int l = 0; l < 3; ++l) {
    int la = l + 1;
    const float* xinB = (l == 0) ? xt : xtb;
    fused_gemm_in_ln<<<512 + 128, 256, 0, stream>>>(
        xcur, Wint + (size_t)la * TWO_DI * D_, cs0b + la * TWO_DI, bWb + la * TWO_DI, xz,
        xinB, Wint + (size_t)l * TWO_DI * D_, cs0b + l * TWO_DI, bWb + l * TWO_DI,
        cconvT + (size_t)l * BSEQ * DI_, W_cv + l * DI_ * 4, xcv_bfB, zbufB);
    fused_convsp_ssm<<<BSEQ * NCHUNK + 256, 256, 0, stream>>>(
        xz, W_cv + la * DI_ * 4, b_cv + la * DI_, Wxt + (size_t)la * NDBL * DI_,
        WdtT + (size_t)la * DI_ * RR, b_dt + la * DI_, Aneg + la * DI_ * NSTATE,
        xcvb, dtb, dblg, cconvT + (size_t)la * BSEQ * DI_, Sb, Pb,
        xcv_bfB, zbufB, Wxt + (size_t)l * NDBL * DI_, WdtT + (size_t)l * DI_ * RR,
        b_dt + l * DI_, Aneg + l * DI_ * NSTATE, Dp + l * DI_,
        hst + (size_t)l * BSEQ * DI_ * NSTATE, y_bfB);
    fused_fin_gout<<<128 + BSEQ * NCHUNK * 32, 256, 0, stream>>>(
        y_bfB, Wot + (size_t)l * D_ * DI_, xinB, xtb,
        dblg, xcvb, xz, dtb, Sb, Pb, Aneg + la * DI_ * NSTATE, Dp + la * DI_,
        yb_bf, hst + (size_t)la * BSEQ * DI_ * NSTATE);
    if (la < 3)
      gemm_out<<<dim3(D_ / 64, CTX / 64), 256, 0, stream>>>(
          yb_bf, Wot + (size_t)la * D_ * DI_, xcur, xcur, D_, DI_);
  }

  // -------- B3 tail --------
  gemm_in_ln<1><<<dim3(16, TGT / 64), 256, 0, stream>>>(
      xtb, Wint + (size_t)3 * TWO_DI * D_, cs0b + 3 * TWO_DI, bWb + 3 * TWO_DI, nullptr,
      cconvT + (size_t)3 * BSEQ * DI_, W_cv + 3 * DI_ * 4, xcv_bfB, zbufB);
  tgt_ssm2<<<256, 256, 0, stream>>>(xcv_bfB, zbufB,
      Wxt + (size_t)3 * NDBL * DI_, WdtT + (size_t)3 * DI_ * RR, b_dt + 3 * DI_,
      Aneg + 3 * DI_ * NSTATE, Dp + 3 * DI_,
      hst + (size_t)3 * BSEQ * DI_ * NSTATE, y_bfB);
  gemm_s<<<dim3(D_ / 32, TGT / 32), 256, 0, stream>>>(
      y_bfB, Wot + (size_t)3 * D_ * DI_, xtb, out, D_, DI_);
}

// Round 6
// 304.513 us; speedup vs baseline: 1.1068x; 1.1068x over previous
//
#include <hip/hip_runtime.h>
#include <hip/hip_bf16.h>

#define D_     256
#define TWO_DI 1024
#define DI_    512
#define NSTATE 16
#define RR     16
#define NDBL   48      // R + 2N
#define BSEQ   8
#define NC     256
#define NCHUNK 16
#define CLEN   16
#define CTX    2048    // 8*256
#define TGT    512     // 8*64

typedef __attribute__((ext_vector_type(8))) short short8v;
typedef __attribute__((ext_vector_type(8))) unsigned short ushort8v;
typedef __attribute__((ext_vector_type(4))) float floatx4;

__device__ __forceinline__ float siluf(float x) { return x / (1.f + __expf(-x)); }
__device__ __forceinline__ float softplusf(float x) {
  return fmaxf(x, 0.f) + log1pf(__expf(-fabsf(x)));
}
__device__ __forceinline__ unsigned short f2bf(float x) {
  unsigned u = __float_as_uint(x);
  u += 0x7fffu + ((u >> 16) & 1u);          // round-to-nearest-even
  return (unsigned short)(u >> 16);
}
__device__ __forceinline__ float bf2f(unsigned short b) {
  return __uint_as_float((unsigned)b << 16);
}

// ---- one-shot prep: W_in'(=g-scaled)/W_o/W_x transpose->bf16, WdtT, Aneg,
//      colsum(W_in') and b@W_in per column (atomicAdd into zeroed cs0/bW) ----
__global__ __launch_bounds__(256) void prep_all(
    const float* __restrict__ W_in, const float* __restrict__ W_o,
    const float* __restrict__ W_x, const float* __restrict__ Alog,
    const float* __restrict__ W_dt,
    const float* __restrict__ ln_g, const float* __restrict__ ln_b,
    unsigned short* __restrict__ Wint, unsigned short* __restrict__ Wot,
    unsigned short* __restrict__ Wxt, float* __restrict__ Aneg,
    float* __restrict__ WdtT, float* __restrict__ cs0, float* __restrict__ bW)
{
  __shared__ float tile[32][33];
  int b = blockIdx.x;
  int tx = threadIdx.x & 31, ty = threadIdx.x >> 5;
  if (b < 1024) {          // W_in: 4 x [256][1024] -> g-scaled bf16 [1024][256] + colsums
    int z = b >> 8, t = b & 255; int cx = t & 31, ry = t >> 5;
    const int R = 256, C = 1024;
    const float* src = W_in + (size_t)z * R * C;
    unsigned short* dst = Wint + (size_t)z * R * C;
    int c0 = cx * 32, r0 = ry * 32;
#pragma unroll
    for (int i = 0; i < 4; ++i)
      tile[ty + i * 8][tx] = src[(size_t)(r0 + ty + i * 8) * C + c0 + tx];
    __syncthreads();
    float gv  = ln_g[z * D_ + r0 + tx];
    float bev = ln_b[z * D_ + r0 + tx];
#pragma unroll
    for (int i = 0; i < 4; ++i) {
      int c = c0 + ty + i * 8;
      float wv = tile[tx][ty + i * 8];
      unsigned short h = f2bf(wv * gv);
      dst[(size_t)c * R + r0 + tx] = h;
      float cs = bf2f(h);          // colsum of the bf16-rounded g-scaled weight
      float bs = bev * wv;
#pragma unroll
      for (int off = 1; off <= 16; off <<= 1) {
        cs += __shfl_xor(cs, off);
        bs += __shfl_xor(bs, off);
      }
      if (tx == 0) {
        atomicAdd(&cs0[z * TWO_DI + c], cs);
        atomicAdd(&bW[z * TWO_DI + c], bs);
      }
    }
    return;
  }
  const float* src; unsigned short* dst; int R, C, cx, ry;
  if (b < 1536) {          // W_o: 4 x [512][256] -> [256][512]
    int bb = b - 1024; int z = bb >> 7, t = bb & 127; cx = t & 7; ry = t >> 3; R = 512; C = 256;
    src = W_o + (size_t)z * R * C; dst = Wot + (size_t)z * R * C;
  } else if (b < 1664) {   // W_x: 4 x [512][48] -> [48][512]
    int bb = b - 1536; int z = bb >> 5, t = bb & 31; cx = t & 1; ry = t >> 1; R = 512; C = 48;
    src = W_x + (size_t)z * R * C; dst = Wxt + (size_t)z * R * C;
  } else if (b < 1792) {   // Aneg
    int i = (b - 1664) * 256 + threadIdx.x;
    if (i < 4 * DI_ * NSTATE) Aneg[i] = -__expf(Alog[i]);
    return;
  } else {                 // WdtT: 4 x [16][512] -> [512][16]
    int i = (b - 1792) * 256 + threadIdx.x;   // 32768 total
    int z = i >> 13, rem = i & 8191, c = rem >> 4, r = rem & 15;
    WdtT[i] = W_dt[(size_t)z * RR * DI_ + r * DI_ + c];
    return;
  }
  int c0 = cx * 32, r0 = ry * 32;
#pragma unroll
  for (int i = 0; i < 4; ++i) {
    int r = r0 + ty + i * 8;
    tile[ty + i * 8][tx] = (r < R && c0 + tx < C) ? src[(size_t)r * C + c0 + tx] : 0.f;
  }
  __syncthreads();
#pragma unroll
  for (int i = 0; i < 4; ++i) {
    int c = c0 + ty + i * 8;
    if (c < C && r0 + tx < R)
      dst[(size_t)c * R + r0 + tx] = f2bf(tile[tx][ty + i * 8]);
  }
}

// ======== in-proj GEMM on RAW x (bf16), LN applied in epilogue via linearity:
//   out[col] = rstd*(acc - mu*cs0[col]) + bW[col]
// EPI=0 -> C (xz).  EPI=1 (tgt): col<512 -> silu(cconv+v*w3)->xcv_bf; else zbuf. ========
template<int EPI>
__device__ __forceinline__ void gemm_in_ln_body(
    unsigned short (*As)[72], unsigned short (*Bs)[72],
    float* mus, float* rstds, int bx, int by,
    const float* __restrict__ X, const unsigned short* __restrict__ Bt,
    const float* __restrict__ cs0, const float* __restrict__ bW,
    float* __restrict__ C,
    const float* __restrict__ cconv, const float* __restrict__ Wc4,
    unsigned short* __restrict__ xcv_bf, float* __restrict__ zbuf)
{
  const int K = D_, N = TWO_DI;
  int tid = threadIdx.x;
  int n0 = bx * 64, m0 = by * 64;
  int w = tid >> 6, lane = tid & 63;
  int lr = lane & 15, kq = lane >> 4;
  int wr = w >> 1, wc = w & 1;
  int srow = tid >> 2, q = tid & 3, schunk = q * 16;
  const float* Apf = &X[(size_t)(m0 + srow) * K];
  // load this thread's 4x16 column slices of its row once; stats from regs
  float4 xr[4][4];
#pragma unroll
  for (int j = 0; j < 4; ++j)
#pragma unroll
    for (int i = 0; i < 4; ++i)
      xr[j][i] = *reinterpret_cast<const float4*>(&Apf[j * 64 + schunk + i * 4]);
  float s = 0.f, sq = 0.f;
#pragma unroll
  for (int j = 0; j < 4; ++j)
#pragma unroll
    for (int i = 0; i < 4; ++i) {
      float4 v = xr[j][i];
      s  += v.x + v.y + v.z + v.w;
      sq += v.x * v.x + v.y * v.y + v.z * v.z + v.w * v.w;
    }
  s += __shfl_xor(s, 1);  s += __shfl_xor(s, 2);
  sq += __shfl_xor(sq, 1); sq += __shfl_xor(sq, 2);
  float mu   = s * (1.f / K);
  float rstd = rsqrtf(sq * (1.f / K) - mu * mu + 1e-5f);
  if (q == 0) { mus[srow] = mu; rstds[srow] = rstd; }
  const unsigned short* Bp = &Bt[(size_t)(n0 + srow) * K + schunk];
  ushort8v b0 = *reinterpret_cast<const ushort8v*>(Bp);
  ushort8v b1 = *reinterpret_cast<const ushort8v*>(Bp + 8);
  floatx4 acc[2][2] = {};
#pragma unroll
  for (int j = 0; j < 4; ++j) {
    __syncthreads();
    {
      ushort8v o0, o1;
#pragma unroll
      for (int i = 0; i < 4; ++i) {
        float4 v = xr[j][i];
        unsigned short e0 = f2bf(v.x), e1 = f2bf(v.y), e2 = f2bf(v.z), e3 = f2bf(v.w);
        if (i < 2) { o0[i*4] = (short)e0; o0[i*4+1] = (short)e1; o0[i*4+2] = (short)e2; o0[i*4+3] = (short)e3; }
        else { int jj = (i - 2) * 4; o1[jj] = (short)e0; o1[jj+1] = (short)e1; o1[jj+2] = (short)e2; o1[jj+3] = (short)e3; }
      }
      *reinterpret_cast<ushort8v*>(&As[srow][schunk])     = o0;
      *reinterpret_cast<ushort8v*>(&As[srow][schunk + 8]) = o1;
    }
    *reinterpret_cast<ushort8v*>(&Bs[srow][schunk])     = b0;
    *reinterpret_cast<ushort8v*>(&Bs[srow][schunk + 8]) = b1;
    __syncthreads();
    if (j < 3) {
      b0 = *reinterpret_cast<const ushort8v*>(Bp + j * 64 + 64);
      b1 = *reinterpret_cast<const ushort8v*>(Bp + j * 64 + 72);
    }
#pragma unroll
    for (int ks = 0; ks < 2; ++ks) {
      short8v af2[2], bf2v[2];
#pragma unroll
      for (int f = 0; f < 2; ++f)
        af2[f] = *reinterpret_cast<const short8v*>(&As[wr * 32 + f * 16 + lr][ks * 32 + kq * 8]);
#pragma unroll
      for (int g2 = 0; g2 < 2; ++g2)
        bf2v[g2] = *reinterpret_cast<const short8v*>(&Bs[wc * 32 + g2 * 16 + lr][ks * 32 + kq * 8]);
#pragma unroll
      for (int f = 0; f < 2; ++f)
#pragma unroll
        for (int g2 = 0; g2 < 2; ++g2)
          acc[f][g2] = __builtin_amdgcn_mfma_f32_16x16x32_bf16(af2[f], bf2v[g2], acc[f][g2], 0, 0, 0);
    }
  }
#pragma unroll
  for (int f = 0; f < 2; ++f)
#pragma unroll
    for (int g2 = 0; g2 < 2; ++g2) {
      int col = n0 + wc * 32 + g2 * 16 + lr;
      float c0v = cs0[col], bwv = bW[col];
#pragma unroll
      for (int r = 0; r < 4; ++r) {
        int rowl = wr * 32 + f * 16 + kq * 4 + r;
        int row  = m0 + rowl;
        float v = rstds[rowl] * (acc[f][g2][r] - mus[rowl] * c0v) + bwv;
        if (EPI == 0) {
          C[(size_t)row * N + col] = v;
        } else {
          int bb = row >> 6;
          if (col < DI_) {
            float sv = siluf(cconv[bb * DI_ + col] + v * Wc4[col * 4 + 3]);
            xcv_bf[(size_t)row * DI_ + col] = f2bf(sv);
          } else {
            zbuf[(size_t)row * DI_ + (col - DI_)] = v;
          }
        }
      }
    }
}

template<int EPI>
__global__ __launch_bounds__(256) void gemm_in_ln(
    const float* __restrict__ X, const unsigned short* __restrict__ Bt,
    const float* __restrict__ cs0, const float* __restrict__ bW,
    float* __restrict__ C,
    const float* __restrict__ cconv, const float* __restrict__ Wc4,
    unsigned short* __restrict__ xcv_bf, float* __restrict__ zbuf)
{
  __shared__ unsigned short As[64][72];
  __shared__ unsigned short Bs[64][72];
  __shared__ float mus[64], rstds[64];
  gemm_in_ln_body<EPI>(As, Bs, mus, rstds, blockIdx.x, blockIdx.y,
                       X, Bt, cs0, bW, C, cconv, Wc4, xcv_bf, zbuf);
}

// fused: A in-proj (512 blocks) + B in-proj EPI=1 (128 blocks)
__global__ __launch_bounds__(256) void fused_gemm_in_ln(
    const float* __restrict__ Xa, const unsigned short* __restrict__ Bta,
    const float* __restrict__ cs0a, const float* __restrict__ bWa,
    float* __restrict__ Ca,
    const float* __restrict__ Xb, const unsigned short* __restrict__ Btb,
    const float* __restrict__ cs0b, const float* __restrict__ bWb,
    const float* __restrict__ cconv, const float* __restrict__ Wc4,
    unsigned short* __restrict__ xcv_bf, float* __restrict__ zbuf)
{
  __shared__ unsigned short As[64][72];
  __shared__ unsigned short Bs[64][72];
  __shared__ float mus[64], rstds[64];
  int f = blockIdx.x;
  if (f < 512)
    gemm_in_ln_body<0>(As, Bs, mus, rstds, f & 15, f >> 4, Xa, Bta, cs0a, bWa,
                       Ca, nullptr, nullptr, nullptr, nullptr);
  else {
    f -= 512;
    gemm_in_ln_body<1>(As, Bs, mus, rstds, f & 15, f >> 4, Xb, Btb, cs0b, bWb,
                       nullptr, cconv, Wc4, xcv_bf, zbuf);
  }
}

// ------- out-proj MFMA GEMM, 64x64 tile, bf16 A, +resid -------
__global__ __launch_bounds__(256) void gemm_out(
    const unsigned short* __restrict__ A, const unsigned short* __restrict__ Bt,
    const float* __restrict__ resid, float* __restrict__ C, int N, int K)
{
  __shared__ unsigned short As[64][72];
  __shared__ unsigned short Bs[64][72];
  int tid = threadIdx.x;
  int n0 = blockIdx.x * 64, m0 = blockIdx.y * 64;
  int w = tid >> 6, lane = tid & 63;
  int lr = lane & 15, kq = lane >> 4;
  int wr = w >> 1, wc = w & 1;
  int srow = tid >> 2, schunk = (tid & 3) * 16;
  const unsigned short* Ap = &A[(size_t)(m0 + srow) * K + schunk];
  const unsigned short* Bp = &Bt[(size_t)(n0 + srow) * K + schunk];
  ushort8v a0 = *reinterpret_cast<const ushort8v*>(Ap);
  ushort8v a1 = *reinterpret_cast<const ushort8v*>(Ap + 8);
  ushort8v b0 = *reinterpret_cast<const ushort8v*>(Bp);
  ushort8v b1 = *reinterpret_cast<const ushort8v*>(Bp + 8);
  floatx4 acc[2][2] = {};
  for (int k0 = 0; k0 < K; k0 += 64) {
    __syncthreads();
    *reinterpret_cast<ushort8v*>(&As[srow][schunk])     = a0;
    *reinterpret_cast<ushort8v*>(&As[srow][schunk + 8]) = a1;
    *reinterpret_cast<ushort8v*>(&Bs[srow][schunk])     = b0;
    *reinterpret_cast<ushort8v*>(&Bs[srow][schunk + 8]) = b1;
    __syncthreads();
    if (k0 + 64 < K) {
      a0 = *reinterpret_cast<const ushort8v*>(Ap + k0 + 64);
      a1 = *reinterpret_cast<const ushort8v*>(Ap + k0 + 72);
      b0 = *reinterpret_cast<const ushort8v*>(Bp + k0 + 64);
      b1 = *reinterpret_cast<const ushort8v*>(Bp + k0 + 72);
    }
#pragma unroll
    for (int ks = 0; ks < 2; ++ks) {
      short8v af[2], bf2v[2];
#pragma unroll
      for (int f = 0; f < 2; ++f)
        af[f] = *reinterpret_cast<const short8v*>(&As[wr * 32 + f * 16 + lr][ks * 32 + kq * 8]);
#pragma unroll
      for (int g2 = 0; g2 < 2; ++g2)
        bf2v[g2] = *reinterpret_cast<const short8v*>(&Bs[wc * 32 + g2 * 16 + lr][ks * 32 + kq * 8]);
#pragma unroll
      for (int f = 0; f < 2; ++f)
#pragma unroll
        for (int g2 = 0; g2 < 2; ++g2)
          acc[f][g2] = __builtin_amdgcn_mfma_f32_16x16x32_bf16(af[f], bf2v[g2], acc[f][g2], 0, 0, 0);
    }
  }
#pragma unroll
  for (int f = 0; f < 2; ++f)
#pragma unroll
    for (int g2 = 0; g2 < 2; ++g2) {
      int col = n0 + wc * 32 + g2 * 16 + lr;
#pragma unroll
      for (int r = 0; r < 4; ++r) {
        int row = m0 + wr * 32 + f * 16 + kq * 4 + r;
        float v = acc[f][g2][r] + resid[(size_t)row * N + col];
        C[(size_t)row * N + col] = v;
      }
    }
}

// ------- small-tile MFMA GEMM: 32x32 tile (tgt out-proj) -------
__device__ __forceinline__ void gemm_s_body(int bx, int by,
    const unsigned short* __restrict__ A, const unsigned short* __restrict__ Bt,
    const float* __restrict__ resid, float* __restrict__ C, int N, int K)
{
  __shared__ unsigned short As[32][72];
  __shared__ unsigned short Bs[32][72];
  int tid = threadIdx.x;
  int n0 = bx * 32, m0 = by * 32;
  int w = tid >> 6, lane = tid & 63;
  int lr = lane & 15, kq = lane >> 4;
  int wr = w >> 1, wc = w & 1;
  int srow = tid >> 3, schunk = (tid & 7) * 8;
  const unsigned short* Ap = &A[(size_t)(m0 + srow) * K + schunk];
  const unsigned short* Bp = &Bt[(size_t)(n0 + srow) * K + schunk];
  ushort8v a0 = *reinterpret_cast<const ushort8v*>(Ap);
  ushort8v b0 = *reinterpret_cast<const ushort8v*>(Bp);
  floatx4 acc = {};
  for (int k0 = 0; k0 < K; k0 += 64) {
    __syncthreads();
    *reinterpret_cast<ushort8v*>(&As[srow][schunk]) = a0;
    *reinterpret_cast<ushort8v*>(&Bs[srow][schunk]) = b0;
    __syncthreads();
    if (k0 + 64 < K) {
      a0 = *reinterpret_cast<const ushort8v*>(Ap + k0 + 64);
      b0 = *reinterpret_cast<const ushort8v*>(Bp + k0 + 64);
    }
#pragma unroll
    for (int ks = 0; ks < 2; ++ks) {
      short8v af = *reinterpret_cast<const short8v*>(&As[wr * 16 + lr][ks * 32 + kq * 8]);
      short8v bf = *reinterpret_cast<const short8v*>(&Bs[wc * 16 + lr][ks * 32 + kq * 8]);
      acc = __builtin_amdgcn_mfma_f32_16x16x32_bf16(af, bf, acc, 0, 0, 0);
    }
  }
  int col = n0 + wc * 16 + lr;
#pragma unroll
  for (int r = 0; r < 4; ++r) {
    int row = m0 + wr * 16 + kq * 4 + r;
    float v = acc[r] + resid[(size_t)row * N + col];
    C[(size_t)row * N + col] = v;
  }
}

__global__ __launch_bounds__(256) void gemm_s(
    const unsigned short* __restrict__ A, const unsigned short* __restrict__ Bt,
    const float* __restrict__ resid, float* __restrict__ C, int N, int K)
{
  gemm_s_body(blockIdx.x, blockIdx.y, A, Bt, resid, C, N, K);
}

// ===== lean ctx conv: conv+silu (reg-cached taps) -> dbl (MFMA) -> dt =====
__device__ __forceinline__ void conv_body_lean(int blk,
    const float* __restrict__ xz, const float* __restrict__ Wc,
    const float* __restrict__ bc, const unsigned short* __restrict__ Wxt,
    const float* __restrict__ WdtT, const float* __restrict__ bdt,
    unsigned short* __restrict__ xcvb, float* __restrict__ dtb,
    float* __restrict__ dblg, float* __restrict__ cconv)
{
  __shared__ unsigned short xcs[16][528];
  __shared__ float dbl_s[16][48];
  int seq = blk >> 4, ch = blk & 15;
  int tok0 = blk * 16;
  int tid = threadIdx.x;
  int base = ch * 16;
#pragma unroll
  for (int hh = 0; hh < 2; ++hh) {
    int c = tid + hh * 256;
    const float4 wv = *reinterpret_cast<const float4*>(&Wc[c * 4]);
    float bcv = bc[c];
    const float* xzs = &xz[(size_t)(seq * NC) * TWO_DI + c];
    float r[19];
#pragma unroll
    for (int i = 0; i < 19; ++i) {
      int tl = base - 3 + i;
      r[i] = (tl >= 0) ? xzs[(size_t)tl * TWO_DI] : 0.f;
    }
#pragma unroll
    for (int t = 0; t < 16; ++t) {
      float acc = bcv + r[t] * wv.x + r[t + 1] * wv.y + r[t + 2] * wv.z + r[t + 3] * wv.w;
      unsigned short sv = f2bf(siluf(acc));
      xcs[t][c] = sv;
      xcvb[(size_t)(tok0 + t) * DI_ + c] = sv;
    }
    if (ch == 15)
      cconv[seq * DI_ + c] = bcv + r[16] * wv.x + r[17] * wv.y + r[18] * wv.z;
  }
  __syncthreads();
  int w = tid >> 6, lane = tid & 63, lr = lane & 15, kq = lane >> 4;
  if (w < 3) {
    floatx4 acc = {};
#pragma unroll
    for (int kc = 0; kc < 16; ++kc) {
      short8v bb = *reinterpret_cast<const short8v*>(&Wxt[(size_t)(w * 16 + lr) * DI_ + kc * 32 + kq * 8]);
      short8v aa = *reinterpret_cast<const short8v*>(&xcs[lr][kc * 32 + kq * 8]);
      acc = __builtin_amdgcn_mfma_f32_16x16x32_bf16(aa, bb, acc, 0, 0, 0);
    }
#pragma unroll
    for (int r2 = 0; r2 < 4; ++r2) {
      int t = kq * 4 + r2, col = w * 16 + lr;
      dbl_s[t][col] = acc[r2];
      dblg[(size_t)(tok0 + t) * NDBL + col] = acc[r2];
    }
  }
  __syncthreads();
#pragma unroll
  for (int hh = 0; hh < 2; ++hh) {
    int c = tid + hh * 256;
    float wr_[16];
    const float4* wt4 = reinterpret_cast<const float4*>(&WdtT[c * 16]);
#pragma unroll
    for (int q = 0; q < 4; ++q) {
      float4 v4 = wt4[q];
      wr_[q * 4] = v4.x; wr_[q * 4 + 1] = v4.y; wr_[q * 4 + 2] = v4.z; wr_[q * 4 + 3] = v4.w;
    }
    float bv = bdt[c];
#pragma unroll
    for (int t = 0; t < 16; ++t) {
      float accd = bv;
#pragma unroll
      for (int r2 = 0; r2 < 16; ++r2) accd += dbl_s[t][r2] * wr_[r2];
      dtb[(size_t)(tok0 + t) * DI_ + c] = softplusf(accd);
    }
  }
}

__global__ __launch_bounds__(256) void conv_lean_kern(
    const float* __restrict__ xz, const float* __restrict__ Wc,
    const float* __restrict__ bc, const unsigned short* __restrict__ Wxt,
    const float* __restrict__ WdtT, const float* __restrict__ bdt,
    unsigned short* __restrict__ xcvb, float* __restrict__ dtb,
    float* __restrict__ dblg, float* __restrict__ cconv)
{
  conv_body_lean(blockIdx.x, xz, Wc, bc, Wxt, WdtT, bdt, xcvb, dtb, dblg, cconv);
}

// ===== pass-1 S,P: 4096 blocks = (128 chunks) x (32 dg), 16 exp/thread =====
__device__ __forceinline__ void sp_body(int b,
    const float* __restrict__ dblg, const unsigned short* __restrict__ xcvb,
    const float* __restrict__ dtb, const float* __restrict__ Aneg,
    float* __restrict__ Sb, float* __restrict__ Pb)
{
  int dg = b & 31, sc = b >> 5;
  int tid = threadIdx.x;
  int tt = tid >> 4, cc = tid & 15;
  int tok0 = sc * CLEN;
  __shared__ float dts[16][17], xs[16][17], Bsh[16][17];
  dts[tt][cc] = dtb[(size_t)(tok0 + tt) * DI_ + dg * 16 + cc];
  xs[tt][cc]  = bf2f(xcvb[(size_t)(tok0 + tt) * DI_ + dg * 16 + cc]);
  Bsh[tt][cc] = dblg[(size_t)(tok0 + tt) * NDBL + RR + cc];
  __syncthreads();
  int dl = tt, n = cc;
  int d = dg * 16 + dl;
  float A = Aneg[d * NSTATE + n];
  float Bn[16];
#pragma unroll
  for (int t = 0; t < CLEN; ++t) Bn[t] = Bsh[t][n];
  float h = 0.f, p = 1.f;
#pragma unroll
  for (int t = 0; t < CLEN; ++t) {
    float dtv = dts[t][dl];
    float dA  = __expf(dtv * A);
    h = fmaf(dA, h, dtv * xs[t][dl] * Bn[t]);
    p *= dA;
  }
  size_t o = ((size_t)sc * DI_ + d) * NSTATE + n;
  Sb[o] = h; Pb[o] = p;
}

__global__ __launch_bounds__(256) void sp_kern(
    const float* __restrict__ dblg, const unsigned short* __restrict__ xcvb,
    const float* __restrict__ dtb, const float* __restrict__ Aneg,
    float* __restrict__ Sb, float* __restrict__ Pb)
{
  sp_body(blockIdx.x, dblg, xcvb, dtb, Aneg, Sb, Pb);
}

// fused: B out-proj gemm_s (128 blocks first) + A sp pass (4096 blocks)
__global__ __launch_bounds__(256) void fused_sp_gout(
    const unsigned short* __restrict__ Ag, const unsigned short* __restrict__ Btg,
    const float* __restrict__ residg, float* __restrict__ Cg,
    const float* __restrict__ dblg, const unsigned short* __restrict__ xcvb,
    const float* __restrict__ dtb, const float* __restrict__ Aneg,
    float* __restrict__ Sb, float* __restrict__ Pb)
{
  if (blockIdx.x < 128) {
    int f = blockIdx.x;
    gemm_s_body(f & 7, f >> 3, Ag, Btg, residg, Cg, D_, DI_);
  } else {
    sp_body(blockIdx.x - 128, dblg, xcvb, dtb, Aneg, Sb, Pb);
  }
}

// ---- scan finalize: prefix-combine entry state, re-scan chunk, C-reduce + gate ----
__global__ __launch_bounds__(256) void scan_fin(
    const float* __restrict__ dblg, const unsigned short* __restrict__ xcvb,
    const float* __restrict__ xz, const float* __restrict__ dtb,
    const float* __restrict__ Sb, const float* __restrict__ Pb,
    const float* __restrict__ Aneg, const float* __restrict__ Dp,
    unsigned short* __restrict__ yb, float* __restrict__ hstate)
{
  int b = blockIdx.x;
  int dg = b & 31, sc = b >> 5;
  int seq = sc >> 4, chunk = sc & 15;
  int tid = threadIdx.x;
  int tt = tid >> 4, cc = tid & 15;
  int tok0 = sc * CLEN;
  __shared__ float dts[16][17], xs[16][17], zs[16][17], Bsh[16][17], Csh[16][17], ys[16][17];
  dts[tt][cc] = dtb[(size_t)(tok0 + tt) * DI_ + dg * 16 + cc];
  xs[tt][cc]  = bf2f(xcvb[(size_t)(tok0 + tt) * DI_ + dg * 16 + cc]);
  zs[tt][cc]  = xz[(size_t)(tok0 + tt) * TWO_DI + DI_ + dg * 16 + cc];
  Bsh[tt][cc] = dblg[(size_t)(tok0 + tt) * NDBL + RR + cc];
  Csh[tt][cc] = dblg[(size_t)(tok0 + tt) * NDBL + RR + NSTATE + cc];
  __syncthreads();
  int dl = tt, n = cc;
  int d = dg * 16 + dl;
  float A  = Aneg[d * NSTATE + n];
  float Dv = Dp[d];
  float Bn[16], Cn[16];
#pragma unroll
  for (int t = 0; t < CLEN; ++t) { Bn[t] = Bsh[t][n]; Cn[t] = Csh[t][n]; }
  float h = 0.f;
  for (int c2 = 0; c2 < chunk; ++c2) {
    size_t o = ((size_t)(seq * NCHUNK + c2) * DI_ + d) * NSTATE + n;
    h = fmaf(Pb[o], h, Sb[o]);
  }
#pragma unroll
  for (int t = 0; t < CLEN; ++t) {
    float dtv = dts[t][dl];
    float xv  = xs[t][dl];
    float dA  = __expf(dtv * A);
    h = fmaf(dA, h, dtv * xv * Bn[t]);
    float p = h * Cn[t];
    p += __shfl_xor(p, 1); p += __shfl_xor(p, 2);
    p += __shfl_xor(p, 4); p += __shfl_xor(p, 8);
    if (n == 0) ys[t][dl] = (p + xv * Dv) * siluf(zs[t][dl]);
  }
  __syncthreads();
  yb[(size_t)(tok0 + tt) * DI_ + dg * 16 + cc] = f2bf(ys[tt][cc]);
  if (chunk == NCHUNK - 1)
    hstate[(size_t)seq * DI_ * NSTATE + d * NSTATE + n] = h;
}

// ---- target SSM, 256 block-ids = (32 token-groups) x (8 ch-groups of 64). ----
__device__ __forceinline__ void ssm_body(int blk,
    const unsigned short* __restrict__ xcv_bf, const float* __restrict__ zbuf,
    const unsigned short* __restrict__ Wx, const float* __restrict__ WdtT_l,
    const float* __restrict__ bdt_l, const float* __restrict__ An_l,
    const float* __restrict__ Dp_l, const float* __restrict__ hs,
    unsigned short* __restrict__ ybf)
{
  __shared__ float dbl_s[16][48];
  int tg = blk >> 3, cg = blk & 7;
  int tok0 = tg * 16;
  int b = tg >> 2;
  int tid = threadIdx.x;
  int w = tid >> 6, lane = tid & 63, lr = lane & 15, kq = lane >> 4;
  if (w < 3) {
    floatx4 acc = {};
#pragma unroll
    for (int kc = 0; kc < 16; ++kc) {
      short8v bb = *reinterpret_cast<const short8v*>(&Wx[(size_t)(w * 16 + lr) * DI_ + kc * 32 + kq * 8]);
      short8v aa = *reinterpret_cast<const short8v*>(&xcv_bf[(size_t)(tok0 + lr) * DI_ + kc * 32 + kq * 8]);
      acc = __builtin_amdgcn_mfma_f32_16x16x32_bf16(aa, bb, acc, 0, 0, 0);
    }
#pragma unroll
    for (int r = 0; r < 4; ++r)
      dbl_s[kq * 4 + r][w * 16 + lr] = acc[r];
  }
  __syncthreads();
  int c = cg * 64 + (tid & 63);
  int t0 = (tid >> 6) * 4;
  float wdt_r[16], An[16], hr[16];
  const float4* wt4 = reinterpret_cast<const float4*>(&WdtT_l[c * 16]);
  const float4* An4 = reinterpret_cast<const float4*>(&An_l[c * NSTATE]);
  const float4* hr4 = reinterpret_cast<const float4*>(&hs[(size_t)b * DI_ * NSTATE + c * NSTATE]);
#pragma unroll
  for (int qq = 0; qq < 4; ++qq) {
    float4 wv = wt4[qq]; wdt_r[qq*4]=wv.x; wdt_r[qq*4+1]=wv.y; wdt_r[qq*4+2]=wv.z; wdt_r[qq*4+3]=wv.w;
    float4 a = An4[qq]; An[qq*4]=a.x; An[qq*4+1]=a.y; An[qq*4+2]=a.z; An[qq*4+3]=a.w;
    float4 hv = hr4[qq]; hr[qq*4]=hv.x; hr[qq*4+1]=hv.y; hr[qq*4+2]=hv.z; hr[qq*4+3]=hv.w;
  }
  float Dv = Dp_l[c], bv = bdt_l[c];
#pragma unroll
  for (int tt = 0; tt < 4; ++tt) {
    int t = t0 + tt;
    float accd = bv;
#pragma unroll
    for (int r = 0; r < 16; ++r) accd += dbl_s[t][r] * wdt_r[r];
    float dtv = softplusf(accd);
    float xv = bf2f(xcv_bf[(size_t)(tok0 + t) * DI_ + c]);
    float coef = dtv * xv;
    float y = 0.f;
#pragma unroll
    for (int n = 0; n < 16; ++n) {
      float hn = fmaf(__expf(dtv * An[n]), hr[n], coef * dbl_s[t][RR + n]);
      y = fmaf(hn, dbl_s[t][RR + NSTATE + n], y);
    }
    float yv = (y + xv * Dv) * siluf(zbuf[(size_t)(tok0 + t) * DI_ + c]);
    ybf[(size_t)(tok0 + t) * DI_ + c] = f2bf(yv);
  }
}

__global__ __launch_bounds__(256) void tgt_ssm2(
    const unsigned short* __restrict__ xcv_bf, const float* __restrict__ zbuf,
    const unsigned short* __restrict__ Wx, const float* __restrict__ WdtT_l,
    const float* __restrict__ bdt_l, const float* __restrict__ An_l,
    const float* __restrict__ Dp_l, const float* __restrict__ hs,
    unsigned short* __restrict__ ybf)
{
  ssm_body(blockIdx.x, xcv_bf, zbuf, Wx, WdtT_l, bdt_l, An_l, Dp_l, hs, ybf);
}

// fused: lean conv for A layer (128 blocks) + tgt SSM for B layer (256 blocks)
__global__ __launch_bounds__(256) void fused_conv_ssm(
    const float* __restrict__ xz, const float* __restrict__ Wc,
    const float* __restrict__ bc, const unsigned short* __restrict__ WxtA,
    const float* __restrict__ WdtTA, const float* __restrict__ bdtA,
    unsigned short* __restrict__ xcvb, float* __restrict__ dtb,
    float* __restrict__ dblg, float* __restrict__ cconv,
    const unsigned short* __restrict__ xcv_bfB, const float* __restrict__ zbufB,
    const unsigned short* __restrict__ WxB, const float* __restrict__ WdtTB,
    const float* __restrict__ bdtB, const float* __restrict__ AnB,
    const float* __restrict__ DpB, const float* __restrict__ hsB,
    unsigned short* __restrict__ ybfB)
{
  if (blockIdx.x < BSEQ * NCHUNK)
    conv_body_lean(blockIdx.x, xz, Wc, bc, WxtA, WdtTA, bdtA,
                   xcvb, dtb, dblg, cconv);
  else
    ssm_body(blockIdx.x - BSEQ * NCHUNK, xcv_bfB, zbufB, WxB, WdtTB, bdtB,
             AnB, DpB, hsB, ybfB);
}

extern "C" void kernel_launch(void* const* d_in, const int* in_sizes, int n_in,
                              void* d_out, int out_size, void* d_ws, size_t ws_size,
                              hipStream_t stream)
{
  const float* xc   = (const float*)d_in[0];
  const float* xt   = (const float*)d_in[1];
  const float* ln_g = (const float*)d_in[2];
  const float* ln_b = (const float*)d_in[3];
  const float* W_in = (const float*)d_in[4];
  const float* W_cv = (const float*)d_in[5];
  const float* b_cv = (const float*)d_in[6];
  const float* W_x  = (const float*)d_in[7];
  const float* W_dt = (const float*)d_in[8];
  const float* b_dt = (const float*)d_in[9];
  const float* Alog = (const float*)d_in[10];
  const float* Dp   = (const float*)d_in[11];
  const float* W_o  = (const float*)d_in[12];
  float* out = (float*)d_out;

  float* ws = (float*)d_ws;
  size_t off = 0;
  auto alloc = [&](size_t n) { float* p = ws + off; off += n; return p; };
  float* xz     = alloc((size_t)CTX * TWO_DI);
  float* dtb    = alloc((size_t)CTX * DI_);
  float* dblg   = alloc((size_t)CTX * NDBL);
  float* xcur   = alloc((size_t)CTX * D_);
  float* Sb     = alloc((size_t)BSEQ * NCHUNK * DI_ * NSTATE);
  float* Pb     = alloc((size_t)BSEQ * NCHUNK * DI_ * NSTATE);
  float* cconvT = alloc((size_t)4 * BSEQ * DI_);
  float* hst    = alloc((size_t)4 * BSEQ * DI_ * NSTATE);
  float* Aneg   = alloc((size_t)4 * DI_ * NSTATE);
  float* WdtT   = alloc((size_t)4 * DI_ * RR);
  float* cs0b   = alloc((size_t)4 * TWO_DI);   // colsum(W') per layer
  float* bWb    = alloc((size_t)4 * TWO_DI);   // b@W per layer (contiguous w/ cs0b)
  float* zbufB  = alloc((size_t)TGT * DI_);
  float* xtb    = alloc((size_t)TGT * D_);
  unsigned short* xcvb    = (unsigned short*)alloc((size_t)CTX * DI_ / 2);
  unsigned short* yb_bf   = (unsigned short*)alloc((size_t)CTX * DI_ / 2);
  unsigned short* xcv_bfB = (unsigned short*)alloc((size_t)TGT * DI_ / 2);
  unsigned short* y_bfB   = (unsigned short*)alloc((size_t)TGT * DI_ / 2);
  unsigned short* Wint    = (unsigned short*)alloc((size_t)4 * TWO_DI * D_ / 2);
  unsigned short* Wot     = (unsigned short*)alloc((size_t)4 * D_ * DI_ / 2);
  unsigned short* Wxt     = (unsigned short*)alloc((size_t)4 * NDBL * DI_ / 2);
  if (off * sizeof(float) > ws_size) return;

  hipMemsetAsync(cs0b, 0, (size_t)8 * TWO_DI * sizeof(float), stream);
  prep_all<<<1920, 256, 0, stream>>>(W_in, W_o, W_x, Alog, W_dt, ln_g, ln_b,
                                     Wint, Wot, Wxt, Aneg, WdtT, cs0b, bWb);

  // -------- A0: in-proj(epilogue-LN) -> conv -> sp -> fin -> out-proj --------
  gemm_in_ln<0><<<dim3(16, CTX / 64), 256, 0, stream>>>(
      xc, Wint, cs0b, bWb, xz, nullptr, nullptr, nullptr, nullptr);
  conv_lean_kern<<<BSEQ * NCHUNK, 256, 0, stream>>>(
      xz, W_cv, b_cv, Wxt, WdtT, b_dt, xcvb, dtb, dblg, cconvT);
  sp_kern<<<BSEQ * NCHUNK * 32, 256, 0, stream>>>(dblg, xcvb, dtb, Aneg, Sb, Pb);
  scan_fin<<<BSEQ * NCHUNK * 32, 256, 0, stream>>>(
      dblg, xcvb, xz, dtb, Sb, Pb, Aneg, Dp, yb_bf, hst);
  gemm_out<<<dim3(D_ / 64, CTX / 64), 256, 0, stream>>>(
      yb_bf, Wot, xc, xcur, D_, DI_);

  // -------- groups: A(l+1) co-scheduled with B(l) --------
  for (int l = 0; l < 3; ++l) {
    int la = l + 1;
    const float* xinB = (l == 0) ? xt : xtb;
    fused_gemm_in_ln<<<512 + 128, 256, 0, stream>>>(
        xcur, Wint + (size_t)la * TWO_DI * D_, cs0b + la * TWO_DI, bWb + la * TWO_DI, xz,
        xinB, Wint + (size_t)l * TWO_DI * D_, cs0b + l * TWO_DI, bWb + l * TWO_DI,
        cconvT + (size_t)l * BSEQ * DI_, W_cv + l * DI_ * 4, xcv_bfB, zbufB);
    fused_conv_ssm<<<BSEQ * NCHUNK + 256, 256, 0, stream>>>(
        xz, W_cv + la * DI_ * 4, b_cv + la * DI_, Wxt + (size_t)la * NDBL * DI_,
        WdtT + (size_t)la * DI_ * RR, b_dt + la * DI_,
        xcvb, dtb, dblg, cconvT + (size_t)la * BSEQ * DI_,
        xcv_bfB, zbufB, Wxt + (size_t)l * NDBL * DI_, WdtT + (size_t)l * DI_ * RR,
        b_dt + l * DI_, Aneg + l * DI_ * NSTATE, Dp + l * DI_,
        hst + (size_t)l * BSEQ * DI_ * NSTATE, y_bfB);
    fused_sp_gout<<<128 + BSEQ * NCHUNK * 32, 256, 0, stream>>>(
        y_bfB, Wot + (size_t)l * D_ * DI_, xinB, xtb,
        dblg, xcvb, dtb, Aneg + la * DI_ * NSTATE, Sb, Pb);
    scan_fin<<<BSEQ * NCHUNK * 32, 256, 0, stream>>>(
        dblg, xcvb, xz, dtb, Sb, Pb, Aneg + la * DI_ * NSTATE, Dp + la * DI_,
        yb_bf, hst + (size_t)la * BSEQ * DI_ * NSTATE);
    if (la < 3)
      gemm_out<<<dim3(D_ / 64, CTX / 64), 256, 0, stream>>>(
          yb_bf, Wot + (size_t)la * D_ * DI_, xcur, xcur, D_, DI_);
  }

  // -------- B3 tail --------
  gemm_in_ln<1><<<dim3(16, TGT / 64), 256, 0, stream>>>(
      xtb, Wint + (size_t)3 * TWO_DI * D_, cs0b + 3 * TWO_DI, bWb + 3 * TWO_DI, nullptr,
      cconvT + (size_t)3 * BSEQ * DI_, W_cv + 3 * DI_ * 4, xcv_bfB, zbufB);
  tgt_ssm2<<<256, 256, 0, stream>>>(xcv_bfB, zbufB,
      Wxt + (size_t)3 * NDBL * DI_, WdtT + (size_t)3 * DI_ * RR, b_dt + 3 * DI_,
      Aneg + 3 * DI_ * NSTATE, Dp + 3 * DI_,
      hst + (size_t)3 * BSEQ * DI_ * NSTATE, y_bfB);
  gemm_s<<<dim3(D_ / 32, TGT / 32), 256, 0, stream>>>(
      y_bfB, Wot + (size_t)3 * D_ * DI_, xtb, out, D_, DI_);
}